// Round 18
// baseline (484.964 us; speedup 1.0000x reference)
//
#include <hip/hip_runtime.h>
#include <math.h>

// R17: 197us/GEMM = R14. Arithmetic: per block-K-step MFMA 931cy + LDS 900cy
// = 1831 ~= 1846 measured -> LDS port and MFMA pipe SERIALIZE; every sync
// change was null because both terms survived. R18: wave decomp 4x2 -> 2x4
// (wave-tile 64x32): B re-read 2x not 4x -> LDS reads halve (4 ds_read_b128
// /thread/K-step); A stays in regs (4x L1 re-read, not LDS). vmcnt(10)
// derived for 10 ops/body. Chain order hh->hl->lh kept -> absmax must stay
// exactly 0.0390625. Watch WRITE_SIZE for spill (~124 live VGPR).

typedef __bf16 bf16;
typedef bf16 bf16x2 __attribute__((ext_vector_type(2)));
typedef bf16 bf16x4 __attribute__((ext_vector_type(4)));
typedef bf16 bf16x8 __attribute__((ext_vector_type(8)));
typedef float f32x4 __attribute__((ext_vector_type(4)));

#define EPS_Q 1e-8f

constexpr int BM = 128, BN = 128, BK = 32;

__device__ __forceinline__ void gload16(const void* g, void* l) {
    __builtin_amdgcn_global_load_lds(
        (const __attribute__((address_space(1))) unsigned int*)g,
        (__attribute__((address_space(3))) unsigned int*)l, 16, 0, 0);
}

// ---------------------------------------------------------------- prep
// Tile format (8KB per 128x32 bf16 tile): slot = kc*128 + row, 8 bf16/slot.
__global__ __launch_bounds__(256)
void split_ew_tiled(const float* __restrict__ in, bf16* __restrict__ h,
                    bf16* __restrict__ l, int K)
{
    const int t = threadIdx.x;
    #pragma unroll
    for (int i = 0; i < 2; ++i) {
        const int s   = t + i * 256;
        const int row = s >> 2;
        const int kc  = s & 3;
        const float* src = in + (size_t)(blockIdx.y * 128 + row) * K
                              + blockIdx.x * 32 + kc * 8;
        const f32x4 v0 = *reinterpret_cast<const f32x4*>(src);
        const f32x4 v1 = *reinterpret_cast<const f32x4*>(src + 4);
        bf16x8 hh, ll;
        #pragma unroll
        for (int e = 0; e < 4; ++e) {
            const bf16 b0 = (bf16)v0[e];
            hh[e] = b0; ll[e] = (bf16)(v0[e] - (float)b0);
            const bf16 b1 = (bf16)v1[e];
            hh[e + 4] = b1; ll[e + 4] = (bf16)(v1[e] - (float)b1);
        }
        const int slot = kc * 128 + row;
        const size_t base = ((size_t)blockIdx.y * gridDim.x + blockIdx.x) * 4096
                          + slot * 8;
        *reinterpret_cast<bf16x8*>(h + base) = hh;
        *reinterpret_cast<bf16x8*>(l + base) = ll;
    }
}

__global__ __launch_bounds__(256)
void split_tr_tiled(const float* __restrict__ in, bf16* __restrict__ h,
                    bf16* __restrict__ l, int Ncols)
{
    const int t = threadIdx.x;
    #pragma unroll
    for (int i = 0; i < 2; ++i) {
        const int s   = t + i * 256;
        const int kc  = s >> 7;
        const int row = s & 127;
        const int sc  = blockIdx.y * 128 + row;
        const int sr  = blockIdx.x * 32 + kc * 8;
        bf16x8 hh, ll;
        #pragma unroll
        for (int j = 0; j < 8; ++j) {
            const float v = in[(size_t)(sr + j) * Ncols + sc];
            const bf16 b = (bf16)v;
            hh[j] = b; ll[j] = (bf16)(v - (float)b);
        }
        const int slot = kc * 128 + row;
        const size_t base = ((size_t)blockIdx.y * gridDim.x + blockIdx.x) * 4096
                          + slot * 8;
        *reinterpret_cast<bf16x8*>(h + base) = hh;
        *reinterpret_cast<bf16x8*>(l + base) = ll;
    }
}

// ------------------------------------------------------ pipelined GEMM
#define MFMA_(a,b,c) __builtin_amdgcn_mfma_f32_16x16x32_bf16((a),(b),(c),0,0,0)

// fA[set][mi]     = hi frag of A rows wm+mi*16
// fA[set][4+mi]   = lo frag
#define LOAD_A(kt, SET)                                                       \
{   const size_t tb_ = (size_t)(kt) * 8192;                                   \
    fA[SET][0] = *reinterpret_cast<const bf16x8*>(pAh + tb_ + offA[0]);       \
    fA[SET][1] = *reinterpret_cast<const bf16x8*>(pAh + tb_ + offA[1]);       \
    fA[SET][2] = *reinterpret_cast<const bf16x8*>(pAh + tb_ + offA[2]);       \
    fA[SET][3] = *reinterpret_cast<const bf16x8*>(pAh + tb_ + offA[3]);       \
    fA[SET][4] = *reinterpret_cast<const bf16x8*>(pAl + tb_ + offA[0]);       \
    fA[SET][5] = *reinterpret_cast<const bf16x8*>(pAl + tb_ + offA[1]);       \
    fA[SET][6] = *reinterpret_cast<const bf16x8*>(pAl + tb_ + offA[2]);       \
    fA[SET][7] = *reinterpret_cast<const bf16x8*>(pAl + tb_ + offA[3]); }

#define STAGE_B(kt, BUF)                                                      \
{   const size_t tB_ = (tileB0 + (kt)) * 8192;                                \
    gload16((const char*)Bh_g + tB_ + so, (char*)sBh[BUF] + so);              \
    gload16((const char*)Bl_g + tB_ + so, (char*)sBl[BUF] + so); }

// W: 10 = steady (leave B(kt+2)+A(kt+1) in flight), 0 = last body
#define BODY(kt, S, ASET, W)                                                  \
{                                                                             \
    if ((kt) + 1 < KT) LOAD_A((kt) + 1, (ASET) ^ 1);                          \
    if ((W) == 10) asm volatile("s_waitcnt vmcnt(10)" ::: "memory");          \
    else           asm volatile("s_waitcnt vmcnt(0)"  ::: "memory");          \
    __builtin_amdgcn_sched_barrier(0);                                        \
    {                                                                         \
        const bf16x8 bh0 = *reinterpret_cast<const bf16x8*>((const char*)sBh[(S)] + offB[0]); \
        const bf16x8 bh1 = *reinterpret_cast<const bf16x8*>((const char*)sBh[(S)] + offB[1]); \
        const bf16x8 bl0 = *reinterpret_cast<const bf16x8*>((const char*)sBl[(S)] + offB[0]); \
        const bf16x8 bl1 = *reinterpret_cast<const bf16x8*>((const char*)sBl[(S)] + offB[1]); \
        __builtin_amdgcn_s_setprio(1);                                        \
        /* pass hh */                                                         \
        acc[0][0] = MFMA_(fA[(ASET)][0], bh0, acc[0][0]);                     \
        acc[0][1] = MFMA_(fA[(ASET)][0], bh1, acc[0][1]);                     \
        acc[1][0] = MFMA_(fA[(ASET)][1], bh0, acc[1][0]);                     \
        acc[1][1] = MFMA_(fA[(ASET)][1], bh1, acc[1][1]);                     \
        acc[2][0] = MFMA_(fA[(ASET)][2], bh0, acc[2][0]);                     \
        acc[2][1] = MFMA_(fA[(ASET)][2], bh1, acc[2][1]);                     \
        acc[3][0] = MFMA_(fA[(ASET)][3], bh0, acc[3][0]);                     \
        acc[3][1] = MFMA_(fA[(ASET)][3], bh1, acc[3][1]);                     \
        /* pass hl */                                                         \
        acc[0][0] = MFMA_(fA[(ASET)][0], bl0, acc[0][0]);                     \
        acc[0][1] = MFMA_(fA[(ASET)][0], bl1, acc[0][1]);                     \
        acc[1][0] = MFMA_(fA[(ASET)][1], bl0, acc[1][0]);                     \
        acc[1][1] = MFMA_(fA[(ASET)][1], bl1, acc[1][1]);                     \
        acc[2][0] = MFMA_(fA[(ASET)][2], bl0, acc[2][0]);                     \
        acc[2][1] = MFMA_(fA[(ASET)][2], bl1, acc[2][1]);                     \
        acc[3][0] = MFMA_(fA[(ASET)][3], bl0, acc[3][0]);                     \
        acc[3][1] = MFMA_(fA[(ASET)][3], bl1, acc[3][1]);                     \
        /* pass lh */                                                         \
        acc[0][0] = MFMA_(fA[(ASET)][4], bh0, acc[0][0]);                     \
        acc[0][1] = MFMA_(fA[(ASET)][4], bh1, acc[0][1]);                     \
        acc[1][0] = MFMA_(fA[(ASET)][5], bh0, acc[1][0]);                     \
        acc[1][1] = MFMA_(fA[(ASET)][5], bh1, acc[1][1]);                     \
        acc[2][0] = MFMA_(fA[(ASET)][6], bh0, acc[2][0]);                     \
        acc[2][1] = MFMA_(fA[(ASET)][6], bh1, acc[2][1]);                     \
        acc[3][0] = MFMA_(fA[(ASET)][7], bh0, acc[3][0]);                     \
        acc[3][1] = MFMA_(fA[(ASET)][7], bh1, acc[3][1]);                     \
        __builtin_amdgcn_s_setprio(0);                                        \
    }                                                                         \
    __builtin_amdgcn_s_barrier();                                             \
    __builtin_amdgcn_sched_barrier(0);                                        \
    if ((kt) + 3 < KT) STAGE_B((kt) + 3, (S));                                \
}

template<int EPI, int KT>
__global__ __launch_bounds__(512, 4)
void qlin_mfmaB(const bf16* __restrict__ Ah_g, const bf16* __restrict__ Al_g,
                const bf16* __restrict__ Bh_g, const bf16* __restrict__ Bl_g,
                int M, int N,
                float* __restrict__ Cf, bf16* __restrict__ Ch, bf16* __restrict__ Cl,
                const float* __restrict__ g_lx, const float* __restrict__ g_lw,
                const float* __restrict__ g_dx, const float* __restrict__ g_cb,
                const float* __restrict__ g_rcb, const float* __restrict__ g_bias)
{
    __shared__ __align__(16) bf16 sBh[3][4096], sBl[3][4096];   // 48 KB
    __shared__ float s_cb[16], s_rcb[16], s_mid[15], s_rmid[15];

    const int tid = threadIdx.x;
    const int ln  = tid & 63;
    const int wid = tid >> 6;

    if (EPI == 1) {
        if (tid < 16) { s_cb[tid] = g_cb[tid]; s_rcb[tid] = g_rcb[tid]; }
        __syncthreads();
        if (tid < 15) {
            s_mid[tid]  = 0.5f * (s_cb[tid] + s_cb[tid + 1]);
            s_rmid[tid] = 0.5f * (s_rcb[tid] + s_rcb[tid + 1]);
        }
    }

    const int wm = (wid >> 2) * 64;    // 2 row-groups (0, 64)
    const int wn = (wid & 3) * 32;     // 4 col-groups (0,32,64,96)
    const int fr = ln & 15;
    const int q  = ln >> 4;            // k-chunk of this lane

    // kc-major tile: byte offset = (kc*128 + row)*16
    int offA[4];
    #pragma unroll
    for (int mi = 0; mi < 4; ++mi)
        offA[mi] = (q * 128 + wm + mi * 16 + fr) * 16;
    const char* pAh = (const char*)Ah_g + (size_t)blockIdx.y * KT * 8192;
    const char* pAl = (const char*)Al_g + (size_t)blockIdx.y * KT * 8192;

    const size_t tileB0 = (size_t)blockIdx.x * KT;
    const int so = tid << 4;

    int offB[2];
    #pragma unroll
    for (int nj = 0; nj < 2; ++nj)
        offB[nj] = (q * 128 + wn + nj * 16 + fr) * 16;

    bf16x8 fA[2][8];
    f32x4 acc[4][2] = {};

    // prologue: A(0) + B tiles 0,1,2; confirm A(0),B(0) (leave B1,B2 = 4)
    LOAD_A(0, 0);
    STAGE_B(0, 0);
    STAGE_B(1, 1);
    STAGE_B(2, 2);
    asm volatile("s_waitcnt vmcnt(4)" ::: "memory");
    __builtin_amdgcn_sched_barrier(0);
    __builtin_amdgcn_s_barrier();
    __builtin_amdgcn_sched_barrier(0);

    // main loop: period 6 aligns S (mod 3) and A-set (mod 2)
    constexpr int LIM = ((KT - 1) / 6) * 6;
    for (int kt = 0; kt < LIM; kt += 6) {
        BODY(kt + 0, 0, 0, 10);
        BODY(kt + 1, 1, 1, 10);
        BODY(kt + 2, 2, 0, 10);
        BODY(kt + 3, 0, 1, 10);
        BODY(kt + 4, 1, 0, 10);
        BODY(kt + 5, 2, 1, 10);
    }
    if constexpr (KT == 128) {          // LIM=126
        BODY(126, 0, 0, 10);
        BODY(127, 1, 1, 0);
    } else {                            // KT==64, LIM=60
        BODY(60, 0, 0, 10);
        BODY(61, 1, 1, 10);
        BODY(62, 2, 0, 10);
        BODY(63, 0, 1, 0);
    }

    // ---- epilogue (16x16 C/D: col=lane&15, row=(lane>>4)*4+reg) ----
    const int rloc = wm + q * 4;
    if (EPI == 1) {
        float mid[15], rmid[15];
        #pragma unroll
        for (int k = 0; k < 15; ++k) { mid[k] = s_mid[k]; rmid[k] = s_rmid[k]; }
        const int NT = N >> 5;
        #pragma unroll
        for (int nj = 0; nj < 2; ++nj) {
            const int c = blockIdx.x * BN + wn + nj * 16 + fr;
            const float lx = g_lx[c], lw = g_lw[c], dx = g_dx[c];
            const float slx = (fabsf(lx) < EPS_Q) ? EPS_Q : lx;
            const float sdx = (fabsf(dx) < EPS_Q) ? EPS_Q : dx;
            const float ilx = 1.0f / slx, isdx = 1.0f / sdx;
            const float c1 = lx * lw, c2 = dx * lw;
            const int tk = c >> 5, kc = (c >> 3) & 3, j = c & 7;
            #pragma unroll
            for (int mi = 0; mi < 4; ++mi)
                #pragma unroll
                for (int r = 0; r < 4; ++r) {
                    const float p = acc[mi][nj][r];
                    const float z = p * ilx;
                    int i1 = 0;
                    #pragma unroll
                    for (int k = 0; k < 15; ++k) i1 += (mid[k] < z) ? 1 : 0;
                    const float zq = s_cb[i1];
                    const float zr = (p - zq * lx) * isdx;
                    int i2 = 0;
                    #pragma unroll
                    for (int k = 0; k < 15; ++k) i2 += (rmid[k] < zr) ? 1 : 0;
                    const float qr = s_rcb[i2];
                    const float v  = zq * c1 + qr * c2;
                    const bf16  vh = (bf16)v;
                    const int rowInTile = rloc + mi * 16 + r;
                    const int slot = kc * 128 + rowInTile;
                    const size_t o = ((size_t)blockIdx.y * NT + tk) * 4096
                                   + slot * 8 + j;
                    Ch[o] = vh;
                    Cl[o] = (bf16)(v - (float)vh);
                }
        }
    } else {
        const int rbase = blockIdx.y * BM + rloc;
        #pragma unroll
        for (int nj = 0; nj < 2; ++nj) {
            const int c = blockIdx.x * BN + wn + nj * 16 + fr;
            const float bv = g_bias[c];
            #pragma unroll
            for (int mi = 0; mi < 4; ++mi)
                #pragma unroll
                for (int r = 0; r < 4; ++r)
                    Cf[(size_t)(rbase + mi * 16 + r) * N + c] = acc[mi][nj][r] + bv;
        }
    }
}

// --------------------------------------------- fallback (R7, validated path)
constexpr int FLDK = BK + 8;

__device__ __forceinline__ bf16x8 ld8(const bf16* p) {
    const bf16x4 a = *reinterpret_cast<const bf16x4*>(p);
    const bf16x4 b = *reinterpret_cast<const bf16x4*>(p + 4);
    return __builtin_shufflevector(a, b, 0, 1, 2, 3, 4, 5, 6, 7);
}

template<int EPI>
__global__ __launch_bounds__(256, 2)
void qlin_mfma(const float* __restrict__ A, const float* __restrict__ B,
               float* __restrict__ C, int M, int N, int K,
               const float* __restrict__ g_lx, const float* __restrict__ g_lw,
               const float* __restrict__ g_dx, const float* __restrict__ g_cb,
               const float* __restrict__ g_rcb, const float* __restrict__ g_bias)
{
    __shared__ bf16 Ah[BM][FLDK], Al[BM][FLDK], Bh[BN][FLDK], Bl[BN][FLDK];
    __shared__ float s_cb[16], s_rcb[16], s_mid[15], s_rmid[15];

    const int tid = threadIdx.x;
    const int bm  = blockIdx.y * BM;
    const int bn  = blockIdx.x * BN;

    if (EPI == 1) {
        if (tid < 16) { s_cb[tid] = g_cb[tid]; s_rcb[tid] = g_rcb[tid]; }
        __syncthreads();
        if (tid < 15) {
            s_mid[tid]  = 0.5f * (s_cb[tid] + s_cb[tid + 1]);
            s_rmid[tid] = 0.5f * (s_rcb[tid] + s_rcb[tid + 1]);
        }
    }

    const int am  = tid >> 1;
    const int ak0 = (tid & 1) * 16;
    const int bk  = (tid >> 4) * 2;
    const int bn0 = (tid & 15) * 8;
    const float* Abase = A + (size_t)(bm + am) * K + ak0;

    f32x4 rA[4], rB[4];
    auto LOADREGS = [&](int kt) {
        const float* ap = Abase + (size_t)kt * BK;
        #pragma unroll
        for (int q = 0; q < 4; ++q)
            rA[q] = *reinterpret_cast<const f32x4*>(ap + q * 4);
        #pragma unroll
        for (int q = 0; q < 4; ++q)
            rB[q] = *reinterpret_cast<const f32x4*>(
                B + (size_t)(kt * BK + bk + (q >> 1)) * N + bn + bn0 + (q & 1) * 4);
    };
    auto WRITELDS = [&]() {
        #pragma unroll
        for (int q = 0; q < 4; ++q) {
            bf16x4 h, l;
            #pragma unroll
            for (int e = 0; e < 4; ++e) {
                const float x = rA[q][e];
                const bf16  hh = (bf16)x;
                h[e] = hh;
                l[e] = (bf16)(x - (float)hh);
            }
            *reinterpret_cast<bf16x4*>(&Ah[am][ak0 + q * 4]) = h;
            *reinterpret_cast<bf16x4*>(&Al[am][ak0 + q * 4]) = l;
        }
        const int js = tid & 7;
        #pragma unroll
        for (int jj = 0; jj < 8; ++jj) {
            const int j = (jj + js) & 7;
            const float x0 = rB[(j >> 2)][j & 3];
            const float x1 = rB[2 + (j >> 2)][j & 3];
            const bf16 h0 = (bf16)x0, h1 = (bf16)x1;
            const bf16 l0 = (bf16)(x0 - (float)h0), l1 = (bf16)(x1 - (float)h1);
            bf16x2 ph = {h0, h1}, pl = {l0, l1};
            *reinterpret_cast<bf16x2*>(&Bh[bn0 + j][bk]) = ph;
            *reinterpret_cast<bf16x2*>(&Bl[bn0 + j][bk]) = pl;
        }
    };

    const int ln  = tid & 63;
    const int wid = tid >> 6;
    const int wm  = (wid >> 1) * 64;
    const int wn  = (wid & 1) * 64;
    const int fr  = ln & 15;
    const int k8  = (ln >> 4) * 8;

    f32x4 acc[4][4] = {};
    const int NK = K / BK;
    LOADREGS(0);
    for (int kt = 0; kt < NK; ++kt) {
        __syncthreads();
        WRITELDS();
        __syncthreads();
        if (kt + 1 < NK) LOADREGS(kt + 1);

        bf16x8 fAh[4], fAl[4];
        #pragma unroll
        for (int mi = 0; mi < 4; ++mi) {
            fAh[mi] = ld8(&Ah[wm + mi * 16 + fr][k8]);
            fAl[mi] = ld8(&Al[wm + mi * 16 + fr][k8]);
        }
        #pragma unroll
        for (int nj = 0; nj < 4; ++nj) {
            const bf16x8 fBh = ld8(&Bh[wn + nj * 16 + fr][k8]);
            const bf16x8 fBl = ld8(&Bl[wn + nj * 16 + fr][k8]);
            #pragma unroll
            for (int mi = 0; mi < 4; ++mi) {
                acc[mi][nj] = MFMA_(fAh[mi], fBh, acc[mi][nj]);
                acc[mi][nj] = MFMA_(fAh[mi], fBl, acc[mi][nj]);
                acc[mi][nj] = MFMA_(fAl[mi], fBh, acc[mi][nj]);
            }
        }
    }

    const int rbase = bm + wm + (ln >> 4) * 4;
    if (EPI == 1) {
        float mid[15], rmid[15];
        #pragma unroll
        for (int k = 0; k < 15; ++k) { mid[k] = s_mid[k]; rmid[k] = s_rmid[k]; }
        #pragma unroll
        for (int nj = 0; nj < 4; ++nj) {
            const int c = bn + wn + nj * 16 + fr;
            const float lx = g_lx[c], lw = g_lw[c], dx = g_dx[c];
            const float slx = (fabsf(lx) < EPS_Q) ? EPS_Q : lx;
            const float sdx = (fabsf(dx) < EPS_Q) ? EPS_Q : dx;
            const float ilx = 1.0f / slx, isdx = 1.0f / sdx;
            const float c1 = lx * lw, c2 = dx * lw;
            #pragma unroll
            for (int mi = 0; mi < 4; ++mi)
                #pragma unroll
                for (int r = 0; r < 4; ++r) {
                    const float p = acc[mi][nj][r];
                    const float z = p * ilx;
                    int i1 = 0;
                    #pragma unroll
                    for (int k = 0; k < 15; ++k) i1 += (mid[k] < z) ? 1 : 0;
                    const float zq = s_cb[i1];
                    const float zr = (p - zq * lx) * isdx;
                    int i2 = 0;
                    #pragma unroll
                    for (int k = 0; k < 15; ++k) i2 += (rmid[k] < zr) ? 1 : 0;
                    const float qr = s_rcb[i2];
                    C[(size_t)(rbase + mi * 16 + r) * N + c] = zq * c1 + qr * c2;
                }
        }
    } else {
        #pragma unroll
        for (int nj = 0; nj < 4; ++nj) {
            const int c = bn + wn + nj * 16 + fr;
            const float bv = g_bias[c];
            #pragma unroll
            for (int mi = 0; mi < 4; ++mi)
                #pragma unroll
                for (int r = 0; r < 4; ++r)
                    C[(size_t)(rbase + mi * 16 + r) * N + c] = acc[mi][nj][r] + bv;
        }
    }
}

// ------------------------------------------------------------------- launch
extern "C" void kernel_launch(void* const* d_in, const int* in_sizes, int n_in,
                              void* d_out, int out_size, void* d_ws, size_t ws_size,
                              hipStream_t stream)
{
    const float* X    = (const float*)d_in[0];
    const float* U    = (const float*)d_in[1];
    const float* lx   = (const float*)d_in[2];
    const float* lw   = (const float*)d_in[3];
    const float* Zw   = (const float*)d_in[4];
    const float* cb   = (const float*)d_in[5];
    const float* dx   = (const float*)d_in[6];
    const float* rcb  = (const float*)d_in[7];
    const float* bias = (const float*)d_in[8];
    float* out = (float*)d_out;

    const int R    = in_sizes[2];
    const int DIN  = in_sizes[1] / R;
    const int M    = in_sizes[0] / DIN;
    const int DOUT = in_sizes[8];

    const size_t szX = (size_t)M * DIN * sizeof(bf16);
    const size_t szU = (size_t)DIN * R * sizeof(bf16);
    const size_t szZ = (size_t)R * DOUT * sizeof(bf16);
    const size_t szV = (size_t)M * R * sizeof(bf16);
    const size_t need = 2 * (szX + szU + szZ + szV);

    const int KT1 = DIN / 32;
    const int KT2 = R / 32;

    if (ws_size >= need && KT1 == 128 && KT2 == 64) {
        char* w = (char*)d_ws;
        bf16* Xh = (bf16*)w;            w += szX;
        bf16* Xl = (bf16*)w;            w += szX;
        bf16* Uh = (bf16*)w;            w += szU;
        bf16* Ul = (bf16*)w;            w += szU;
        bf16* Zh = (bf16*)w;            w += szZ;
        bf16* Zl = (bf16*)w;            w += szZ;
        bf16* Vh = (bf16*)w;            w += szV;
        bf16* Vl = (bf16*)w;

        split_ew_tiled<<<dim3(DIN / 32, M / 128), dim3(256), 0, stream>>>(
            X, Xh, Xl, DIN);
        split_tr_tiled<<<dim3(DIN / 32, R / 128), dim3(256), 0, stream>>>(
            U, Uh, Ul, R);
        split_tr_tiled<<<dim3(R / 32, DOUT / 128), dim3(256), 0, stream>>>(
            Zw, Zh, Zl, DOUT);

        qlin_mfmaB<1, 128><<<dim3(R / BN, M / BM), dim3(512), 0, stream>>>(
            Xh, Xl, Uh, Ul, M, R, nullptr, Vh, Vl,
            lx, lw, dx, cb, rcb, nullptr);
        qlin_mfmaB<2, 64><<<dim3(DOUT / BN, M / BM), dim3(512), 0, stream>>>(
            Vh, Vl, Zh, Zl, M, DOUT, out, nullptr, nullptr,
            nullptr, nullptr, nullptr, nullptr, nullptr, bias);
    } else {
        float* V = (float*)d_ws;
        qlin_mfma<1><<<dim3(R / BN, M / BM), dim3(256), 0, stream>>>(
            X, U, V, M, R, DIN, lx, lw, dx, cb, rcb, nullptr);
        qlin_mfma<2><<<dim3(DOUT / BN, M / BM), dim3(256), 0, stream>>>(
            V, Zw, out, M, DOUT, R, nullptr, nullptr, nullptr, nullptr, nullptr, bias);
    }
}

// Round 19
// 421.534 us; speedup vs baseline: 1.1505x; 1.1505x over previous
//
#include <hip/hip_runtime.h>
#include <math.h>

// R18: spill regression (WRITE 49.6MB). Model update: R13 (-37% LDS) null ->
// not LDS-BW; consistent story = operand-delivery per MFMA (24 MFMA / 16
// fetches). R19: register blocking 2x -- 128x256 block, wave-tile 64x64,
// 48 MFMA / 16 fetches. acc 4x4 (64 AGPR) + single-set fA (32 VGPR, loads
// issued after last use, no dbuf) fits 256-cap -> no spill. B 3-buf LDS
// (2 tiles/buf, 96KB), vmcnt(4), stage kt+3. Chain hh->hl->lh unchanged ->
// absmax must stay exactly 0.0390625.

typedef __bf16 bf16;
typedef bf16 bf16x2 __attribute__((ext_vector_type(2)));
typedef bf16 bf16x4 __attribute__((ext_vector_type(4)));
typedef bf16 bf16x8 __attribute__((ext_vector_type(8)));
typedef float f32x4 __attribute__((ext_vector_type(4)));

#define EPS_Q 1e-8f

constexpr int BM = 128, BN = 128, BK = 32;   // fallback geometry
constexpr int BN2 = 256;                     // R19 block width

__device__ __forceinline__ void gload16(const void* g, void* l) {
    __builtin_amdgcn_global_load_lds(
        (const __attribute__((address_space(1))) unsigned int*)g,
        (__attribute__((address_space(3))) unsigned int*)l, 16, 0, 0);
}

// ---------------------------------------------------------------- prep
// Tile format (8KB per 128x32 bf16 tile): slot = kc*128 + row, 8 bf16/slot.
__global__ __launch_bounds__(256)
void split_ew_tiled(const float* __restrict__ in, bf16* __restrict__ h,
                    bf16* __restrict__ l, int K)
{
    const int t = threadIdx.x;
    #pragma unroll
    for (int i = 0; i < 2; ++i) {
        const int s   = t + i * 256;
        const int row = s >> 2;
        const int kc  = s & 3;
        const float* src = in + (size_t)(blockIdx.y * 128 + row) * K
                              + blockIdx.x * 32 + kc * 8;
        const f32x4 v0 = *reinterpret_cast<const f32x4*>(src);
        const f32x4 v1 = *reinterpret_cast<const f32x4*>(src + 4);
        bf16x8 hh, ll;
        #pragma unroll
        for (int e = 0; e < 4; ++e) {
            const bf16 b0 = (bf16)v0[e];
            hh[e] = b0; ll[e] = (bf16)(v0[e] - (float)b0);
            const bf16 b1 = (bf16)v1[e];
            hh[e + 4] = b1; ll[e + 4] = (bf16)(v1[e] - (float)b1);
        }
        const int slot = kc * 128 + row;
        const size_t base = ((size_t)blockIdx.y * gridDim.x + blockIdx.x) * 4096
                          + slot * 8;
        *reinterpret_cast<bf16x8*>(h + base) = hh;
        *reinterpret_cast<bf16x8*>(l + base) = ll;
    }
}

__global__ __launch_bounds__(256)
void split_tr_tiled(const float* __restrict__ in, bf16* __restrict__ h,
                    bf16* __restrict__ l, int Ncols)
{
    const int t = threadIdx.x;
    #pragma unroll
    for (int i = 0; i < 2; ++i) {
        const int s   = t + i * 256;
        const int kc  = s >> 7;
        const int row = s & 127;
        const int sc  = blockIdx.y * 128 + row;
        const int sr  = blockIdx.x * 32 + kc * 8;
        bf16x8 hh, ll;
        #pragma unroll
        for (int j = 0; j < 8; ++j) {
            const float v = in[(size_t)(sr + j) * Ncols + sc];
            const bf16 b = (bf16)v;
            hh[j] = b; ll[j] = (bf16)(v - (float)b);
        }
        const int slot = kc * 128 + row;
        const size_t base = ((size_t)blockIdx.y * gridDim.x + blockIdx.x) * 4096
                          + slot * 8;
        *reinterpret_cast<bf16x8*>(h + base) = hh;
        *reinterpret_cast<bf16x8*>(l + base) = ll;
    }
}

// ------------------------------------------------------ R19 GEMM
#define MFMA_(a,b,c) __builtin_amdgcn_mfma_f32_16x16x32_bf16((a),(b),(c),0,0,0)

// A hi frags -> fA[0..3], lo -> fA[4..7] (single set)
#define LOAD_A_HI(kt)                                                         \
{   const size_t tb_ = (size_t)(kt) * 8192;                                   \
    fA[0] = *reinterpret_cast<const bf16x8*>(pAh + tb_ + offA[0]);            \
    fA[1] = *reinterpret_cast<const bf16x8*>(pAh + tb_ + offA[1]);            \
    fA[2] = *reinterpret_cast<const bf16x8*>(pAh + tb_ + offA[2]);            \
    fA[3] = *reinterpret_cast<const bf16x8*>(pAh + tb_ + offA[3]); }
#define LOAD_A_LO(kt)                                                         \
{   const size_t tb_ = (size_t)(kt) * 8192;                                   \
    fA[4] = *reinterpret_cast<const bf16x8*>(pAl + tb_ + offA[0]);            \
    fA[5] = *reinterpret_cast<const bf16x8*>(pAl + tb_ + offA[1]);            \
    fA[6] = *reinterpret_cast<const bf16x8*>(pAl + tb_ + offA[2]);            \
    fA[7] = *reinterpret_cast<const bf16x8*>(pAl + tb_ + offA[3]); }

// stage both col-tiles (2bx, 2bx+1) of K-tile kt into buffer BUF (4 ops)
#define STAGE_B(kt, BUF)                                                      \
{   const size_t t0_ = (tileB0 + (size_t)(kt)) * 8192;                        \
    const size_t t1_ = (tileB0 + KTI + (size_t)(kt)) * 8192;                  \
    gload16((const char*)Bh_g + t0_ + so, (char*)sBh[BUF] + so);              \
    gload16((const char*)Bh_g + t1_ + so, (char*)sBh[BUF] + 8192 + so);       \
    gload16((const char*)Bl_g + t0_ + so, (char*)sBl[BUF] + so);              \
    gload16((const char*)Bl_g + t1_ + so, (char*)sBl[BUF] + 8192 + so); }

// W: 4 = steady, 0 = last body
#define BODY(kt, S, W)                                                        \
{                                                                             \
    if ((W) == 4) asm volatile("s_waitcnt vmcnt(4)" ::: "memory");            \
    else          asm volatile("s_waitcnt vmcnt(0)" ::: "memory");            \
    __builtin_amdgcn_sched_barrier(0);                                        \
    {                                                                         \
        const bf16x8 bh0 = *reinterpret_cast<const bf16x8*>((const char*)sBh[(S)] + offB[0]); \
        const bf16x8 bh1 = *reinterpret_cast<const bf16x8*>((const char*)sBh[(S)] + offB[1]); \
        const bf16x8 bh2 = *reinterpret_cast<const bf16x8*>((const char*)sBh[(S)] + offB[2]); \
        const bf16x8 bh3 = *reinterpret_cast<const bf16x8*>((const char*)sBh[(S)] + offB[3]); \
        const bf16x8 bl0 = *reinterpret_cast<const bf16x8*>((const char*)sBl[(S)] + offB[0]); \
        const bf16x8 bl1 = *reinterpret_cast<const bf16x8*>((const char*)sBl[(S)] + offB[1]); \
        const bf16x8 bl2 = *reinterpret_cast<const bf16x8*>((const char*)sBl[(S)] + offB[2]); \
        const bf16x8 bl3 = *reinterpret_cast<const bf16x8*>((const char*)sBl[(S)] + offB[3]); \
        __builtin_amdgcn_s_setprio(1);                                        \
        /* pass hh */                                                         \
        acc[0][0]=MFMA_(fA[0],bh0,acc[0][0]); acc[0][1]=MFMA_(fA[0],bh1,acc[0][1]); \
        acc[1][0]=MFMA_(fA[1],bh0,acc[1][0]); acc[1][1]=MFMA_(fA[1],bh1,acc[1][1]); \
        acc[2][0]=MFMA_(fA[2],bh0,acc[2][0]); acc[2][1]=MFMA_(fA[2],bh1,acc[2][1]); \
        acc[3][0]=MFMA_(fA[3],bh0,acc[3][0]); acc[3][1]=MFMA_(fA[3],bh1,acc[3][1]); \
        acc[0][2]=MFMA_(fA[0],bh2,acc[0][2]); acc[0][3]=MFMA_(fA[0],bh3,acc[0][3]); \
        acc[1][2]=MFMA_(fA[1],bh2,acc[1][2]); acc[1][3]=MFMA_(fA[1],bh3,acc[1][3]); \
        acc[2][2]=MFMA_(fA[2],bh2,acc[2][2]); acc[2][3]=MFMA_(fA[2],bh3,acc[2][3]); \
        acc[3][2]=MFMA_(fA[3],bh2,acc[3][2]); acc[3][3]=MFMA_(fA[3],bh3,acc[3][3]); \
        /* pass hl */                                                         \
        acc[0][0]=MFMA_(fA[0],bl0,acc[0][0]); acc[0][1]=MFMA_(fA[0],bl1,acc[0][1]); \
        acc[1][0]=MFMA_(fA[1],bl0,acc[1][0]); acc[1][1]=MFMA_(fA[1],bl1,acc[1][1]); \
        acc[2][0]=MFMA_(fA[2],bl0,acc[2][0]); acc[2][1]=MFMA_(fA[2],bl1,acc[2][1]); \
        acc[3][0]=MFMA_(fA[3],bl0,acc[3][0]); acc[3][1]=MFMA_(fA[3],bl1,acc[3][1]); \
        acc[0][2]=MFMA_(fA[0],bl2,acc[0][2]); acc[0][3]=MFMA_(fA[0],bl3,acc[0][3]); \
        acc[1][2]=MFMA_(fA[1],bl2,acc[1][2]); acc[1][3]=MFMA_(fA[1],bl3,acc[1][3]); \
        acc[2][2]=MFMA_(fA[2],bl2,acc[2][2]); acc[2][3]=MFMA_(fA[2],bl3,acc[2][3]); \
        acc[3][2]=MFMA_(fA[3],bl2,acc[3][2]); acc[3][3]=MFMA_(fA[3],bl3,acc[3][3]); \
        __builtin_amdgcn_s_setprio(0);                                        \
        if ((kt) + 1 < KT) LOAD_A_HI((kt) + 1)   /* fA[0..3] free now */      \
        __builtin_amdgcn_s_setprio(1);                                        \
        /* pass lh */                                                         \
        acc[0][0]=MFMA_(fA[4],bh0,acc[0][0]); acc[0][1]=MFMA_(fA[4],bh1,acc[0][1]); \
        acc[1][0]=MFMA_(fA[5],bh0,acc[1][0]); acc[1][1]=MFMA_(fA[5],bh1,acc[1][1]); \
        acc[2][0]=MFMA_(fA[6],bh0,acc[2][0]); acc[2][1]=MFMA_(fA[6],bh1,acc[2][1]); \
        acc[3][0]=MFMA_(fA[7],bh0,acc[3][0]); acc[3][1]=MFMA_(fA[7],bh1,acc[3][1]); \
        acc[0][2]=MFMA_(fA[4],bh2,acc[0][2]); acc[0][3]=MFMA_(fA[4],bh3,acc[0][3]); \
        acc[1][2]=MFMA_(fA[5],bh2,acc[1][2]); acc[1][3]=MFMA_(fA[5],bh3,acc[1][3]); \
        acc[2][2]=MFMA_(fA[6],bh2,acc[2][2]); acc[2][3]=MFMA_(fA[6],bh3,acc[2][3]); \
        acc[3][2]=MFMA_(fA[7],bh2,acc[3][2]); acc[3][3]=MFMA_(fA[7],bh3,acc[3][3]); \
        __builtin_amdgcn_s_setprio(0);                                        \
        if ((kt) + 1 < KT) LOAD_A_LO((kt) + 1)   /* fA[4..7] free now */      \
    }                                                                         \
    __builtin_amdgcn_s_barrier();                                             \
    __builtin_amdgcn_sched_barrier(0);                                        \
    if ((kt) + 3 < KT) STAGE_B((kt) + 3, (S));                                \
}

template<int EPI, int KT>
__global__ __launch_bounds__(512, 2)
void qlin_mfmaC(const bf16* __restrict__ Ah_g, const bf16* __restrict__ Al_g,
                const bf16* __restrict__ Bh_g, const bf16* __restrict__ Bl_g,
                int M, int N,
                float* __restrict__ Cf, bf16* __restrict__ Ch, bf16* __restrict__ Cl,
                const float* __restrict__ g_lx, const float* __restrict__ g_lw,
                const float* __restrict__ g_dx, const float* __restrict__ g_cb,
                const float* __restrict__ g_rcb, const float* __restrict__ g_bias)
{
    __shared__ __align__(16) bf16 sBh[3][8192], sBl[3][8192];   // 96 KB
    __shared__ float s_cb[16], s_rcb[16], s_mid[15], s_rmid[15];

    const int tid = threadIdx.x;
    const int ln  = tid & 63;
    const int wid = tid >> 6;
    const int KTI = KT;                     // col-tile stride in tiles

    if (EPI == 1) {
        if (tid < 16) { s_cb[tid] = g_cb[tid]; s_rcb[tid] = g_rcb[tid]; }
        __syncthreads();
        if (tid < 15) {
            s_mid[tid]  = 0.5f * (s_cb[tid] + s_cb[tid + 1]);
            s_rmid[tid] = 0.5f * (s_rcb[tid] + s_rcb[tid + 1]);
        }
    }

    const int wm = (wid >> 2) * 64;         // 2 row groups (0,64)
    const int wn = (wid & 3) * 64;          // 4 col groups (0,64,128,192)
    const int fr = ln & 15;
    const int q  = ln >> 4;

    // kc-major tile: byte offset = (kc*128 + row)*16
    int offA[4];
    #pragma unroll
    for (int mi = 0; mi < 4; ++mi)
        offA[mi] = (q * 128 + wm + mi * 16 + fr) * 16;
    const char* pAh = (const char*)Ah_g + (size_t)blockIdx.y * KT * 8192;
    const char* pAl = (const char*)Al_g + (size_t)blockIdx.y * KT * 8192;

    const size_t tileB0 = (size_t)blockIdx.x * 2 * KT;   // first of 2 col-tiles
    const int so = tid << 4;

    int offB[4];
    #pragma unroll
    for (int nj = 0; nj < 4; ++nj) {
        const int cb = wn + nj * 16 + fr;   // col in 256-wide block
        offB[nj] = (cb >> 7) * 8192 + (q * 128 + (cb & 127)) * 16;
    }

    bf16x8 fA[8];
    f32x4 acc[4][4] = {};

    // prologue
    STAGE_B(0, 0);
    LOAD_A_HI(0) LOAD_A_LO(0)
    STAGE_B(1, 1);
    STAGE_B(2, 2);
    asm volatile("s_waitcnt vmcnt(8)" ::: "memory");   // B0 + A0 done
    __builtin_amdgcn_sched_barrier(0);
    __builtin_amdgcn_s_barrier();
    __builtin_amdgcn_sched_barrier(0);

    constexpr int NB   = (KT - 1) % 3;      // bodies after main (before last)
    constexpr int MAIN = (KT - 1) - NB;
    for (int kt = 0; kt < MAIN; kt += 3) {
        BODY(kt,     0, 4);
        BODY(kt + 1, 1, 4);
        BODY(kt + 2, 2, 4);
    }
    if constexpr (NB >= 1) { BODY(MAIN,     0, 4); }
    if constexpr (NB >= 2) { BODY(MAIN + 1, 1, 4); }
    { constexpr int SL = (KT - 1) % 3; BODY(KT - 1, SL, 0); }

    // ---- epilogue (16x16 C/D: col=lane&15, row=(lane>>4)*4+reg) ----
    const int rloc = wm + q * 4;
    if (EPI == 1) {
        float mid[15], rmid[15];
        #pragma unroll
        for (int k = 0; k < 15; ++k) { mid[k] = s_mid[k]; rmid[k] = s_rmid[k]; }
        const int NT = N >> 5;
        #pragma unroll
        for (int nj = 0; nj < 4; ++nj) {
            const int c = blockIdx.x * BN2 + wn + nj * 16 + fr;
            const float lx = g_lx[c], lw = g_lw[c], dx = g_dx[c];
            const float slx = (fabsf(lx) < EPS_Q) ? EPS_Q : lx;
            const float sdx = (fabsf(dx) < EPS_Q) ? EPS_Q : dx;
            const float ilx = 1.0f / slx, isdx = 1.0f / sdx;
            const float c1 = lx * lw, c2 = dx * lw;
            const int tk = c >> 5, kc = (c >> 3) & 3, j = c & 7;
            #pragma unroll
            for (int mi = 0; mi < 4; ++mi)
                #pragma unroll
                for (int r = 0; r < 4; ++r) {
                    const float p = acc[mi][nj][r];
                    const float z = p * ilx;
                    int i1 = 0;
                    #pragma unroll
                    for (int k = 0; k < 15; ++k) i1 += (mid[k] < z) ? 1 : 0;
                    const float zq = s_cb[i1];
                    const float zr = (p - zq * lx) * isdx;
                    int i2 = 0;
                    #pragma unroll
                    for (int k = 0; k < 15; ++k) i2 += (rmid[k] < zr) ? 1 : 0;
                    const float qr = s_rcb[i2];
                    const float v  = zq * c1 + qr * c2;
                    const bf16  vh = (bf16)v;
                    const int rowInTile = rloc + mi * 16 + r;
                    const int slot = kc * 128 + rowInTile;
                    const size_t o = ((size_t)blockIdx.y * NT + tk) * 4096
                                   + slot * 8 + j;
                    Ch[o] = vh;
                    Cl[o] = (bf16)(v - (float)vh);
                }
        }
    } else {
        const int rbase = blockIdx.y * BM + rloc;
        #pragma unroll
        for (int nj = 0; nj < 4; ++nj) {
            const int c = blockIdx.x * BN2 + wn + nj * 16 + fr;
            const float bv = g_bias[c];
            #pragma unroll
            for (int mi = 0; mi < 4; ++mi)
                #pragma unroll
                for (int r = 0; r < 4; ++r)
                    Cf[(size_t)(rbase + mi * 16 + r) * N + c] = acc[mi][nj][r] + bv;
        }
    }
}

// --------------------------------------------- fallback (R7, validated path)
constexpr int FLDK = BK + 8;

__device__ __forceinline__ bf16x8 ld8(const bf16* p) {
    const bf16x4 a = *reinterpret_cast<const bf16x4*>(p);
    const bf16x4 b = *reinterpret_cast<const bf16x4*>(p + 4);
    return __builtin_shufflevector(a, b, 0, 1, 2, 3, 4, 5, 6, 7);
}

template<int EPI>
__global__ __launch_bounds__(256, 2)
void qlin_mfma(const float* __restrict__ A, const float* __restrict__ B,
               float* __restrict__ C, int M, int N, int K,
               const float* __restrict__ g_lx, const float* __restrict__ g_lw,
               const float* __restrict__ g_dx, const float* __restrict__ g_cb,
               const float* __restrict__ g_rcb, const float* __restrict__ g_bias)
{
    __shared__ bf16 Ah[BM][FLDK], Al[BM][FLDK], Bh[BN][FLDK], Bl[BN][FLDK];
    __shared__ float s_cb[16], s_rcb[16], s_mid[15], s_rmid[15];

    const int tid = threadIdx.x;
    const int bm  = blockIdx.y * BM;
    const int bn  = blockIdx.x * BN;

    if (EPI == 1) {
        if (tid < 16) { s_cb[tid] = g_cb[tid]; s_rcb[tid] = g_rcb[tid]; }
        __syncthreads();
        if (tid < 15) {
            s_mid[tid]  = 0.5f * (s_cb[tid] + s_cb[tid + 1]);
            s_rmid[tid] = 0.5f * (s_rcb[tid] + s_rcb[tid + 1]);
        }
    }

    const int am  = tid >> 1;
    const int ak0 = (tid & 1) * 16;
    const int bk  = (tid >> 4) * 2;
    const int bn0 = (tid & 15) * 8;
    const float* Abase = A + (size_t)(bm + am) * K + ak0;

    f32x4 rA[4], rB[4];
    auto LOADREGS = [&](int kt) {
        const float* ap = Abase + (size_t)kt * BK;
        #pragma unroll
        for (int q = 0; q < 4; ++q)
            rA[q] = *reinterpret_cast<const f32x4*>(ap + q * 4);
        #pragma unroll
        for (int q = 0; q < 4; ++q)
            rB[q] = *reinterpret_cast<const f32x4*>(
                B + (size_t)(kt * BK + bk + (q >> 1)) * N + bn + bn0 + (q & 1) * 4);
    };
    auto WRITELDS = [&]() {
        #pragma unroll
        for (int q = 0; q < 4; ++q) {
            bf16x4 h, l;
            #pragma unroll
            for (int e = 0; e < 4; ++e) {
                const float x = rA[q][e];
                const bf16  hh = (bf16)x;
                h[e] = hh;
                l[e] = (bf16)(x - (float)hh);
            }
            *reinterpret_cast<bf16x4*>(&Ah[am][ak0 + q * 4]) = h;
            *reinterpret_cast<bf16x4*>(&Al[am][ak0 + q * 4]) = l;
        }
        const int js = tid & 7;
        #pragma unroll
        for (int jj = 0; jj < 8; ++jj) {
            const int j = (jj + js) & 7;
            const float x0 = rB[(j >> 2)][j & 3];
            const float x1 = rB[2 + (j >> 2)][j & 3];
            const bf16 h0 = (bf16)x0, h1 = (bf16)x1;
            const bf16 l0 = (bf16)(x0 - (float)h0), l1 = (bf16)(x1 - (float)h1);
            bf16x2 ph = {h0, h1}, pl = {l0, l1};
            *reinterpret_cast<bf16x2*>(&Bh[bn0 + j][bk]) = ph;
            *reinterpret_cast<bf16x2*>(&Bl[bn0 + j][bk]) = pl;
        }
    };

    const int ln  = tid & 63;
    const int wid = tid >> 6;
    const int wm  = (wid >> 1) * 64;
    const int wn  = (wid & 1) * 64;
    const int fr  = ln & 15;
    const int k8  = (ln >> 4) * 8;

    f32x4 acc[4][4] = {};
    const int NK = K / BK;
    LOADREGS(0);
    for (int kt = 0; kt < NK; ++kt) {
        __syncthreads();
        WRITELDS();
        __syncthreads();
        if (kt + 1 < NK) LOADREGS(kt + 1);

        bf16x8 fAh[4], fAl[4];
        #pragma unroll
        for (int mi = 0; mi < 4; ++mi) {
            fAh[mi] = ld8(&Ah[wm + mi * 16 + fr][k8]);
            fAl[mi] = ld8(&Al[wm + mi * 16 + fr][k8]);
        }
        #pragma unroll
        for (int nj = 0; nj < 4; ++nj) {
            const bf16x8 fBh = ld8(&Bh[wn + nj * 16 + fr][k8]);
            const bf16x8 fBl = ld8(&Bl[wn + nj * 16 + fr][k8]);
            #pragma unroll
            for (int mi = 0; mi < 4; ++mi) {
                acc[mi][nj] = MFMA_(fAh[mi], fBh, acc[mi][nj]);
                acc[mi][nj] = MFMA_(fAh[mi], fBl, acc[mi][nj]);
                acc[mi][nj] = MFMA_(fAl[mi], fBh, acc[mi][nj]);
            }
        }
    }

    const int rbase = bm + wm + (ln >> 4) * 4;
    if (EPI == 1) {
        float mid[15], rmid[15];
        #pragma unroll
        for (int k = 0; k < 15; ++k) { mid[k] = s_mid[k]; rmid[k] = s_rmid[k]; }
        #pragma unroll
        for (int nj = 0; nj < 4; ++nj) {
            const int c = bn + wn + nj * 16 + fr;
            const float lx = g_lx[c], lw = g_lw[c], dx = g_dx[c];
            const float slx = (fabsf(lx) < EPS_Q) ? EPS_Q : lx;
            const float sdx = (fabsf(dx) < EPS_Q) ? EPS_Q : dx;
            const float ilx = 1.0f / slx, isdx = 1.0f / sdx;
            const float c1 = lx * lw, c2 = dx * lw;
            #pragma unroll
            for (int mi = 0; mi < 4; ++mi)
                #pragma unroll
                for (int r = 0; r < 4; ++r) {
                    const float p = acc[mi][nj][r];
                    const float z = p * ilx;
                    int i1 = 0;
                    #pragma unroll
                    for (int k = 0; k < 15; ++k) i1 += (mid[k] < z) ? 1 : 0;
                    const float zq = s_cb[i1];
                    const float zr = (p - zq * lx) * isdx;
                    int i2 = 0;
                    #pragma unroll
                    for (int k = 0; k < 15; ++k) i2 += (rmid[k] < zr) ? 1 : 0;
                    const float qr = s_rcb[i2];
                    C[(size_t)(rbase + mi * 16 + r) * N + c] = zq * c1 + qr * c2;
                }
        }
    } else {
        #pragma unroll
        for (int nj = 0; nj < 4; ++nj) {
            const int c = bn + wn + nj * 16 + fr;
            const float bv = g_bias[c];
            #pragma unroll
            for (int mi = 0; mi < 4; ++mi)
                #pragma unroll
                for (int r = 0; r < 4; ++r)
                    C[(size_t)(rbase + mi * 16 + r) * N + c] = acc[mi][nj][r] + bv;
        }
    }
}

// ------------------------------------------------------------------- launch
extern "C" void kernel_launch(void* const* d_in, const int* in_sizes, int n_in,
                              void* d_out, int out_size, void* d_ws, size_t ws_size,
                              hipStream_t stream)
{
    const float* X    = (const float*)d_in[0];
    const float* U    = (const float*)d_in[1];
    const float* lx   = (const float*)d_in[2];
    const float* lw   = (const float*)d_in[3];
    const float* Zw   = (const float*)d_in[4];
    const float* cb   = (const float*)d_in[5];
    const float* dx   = (const float*)d_in[6];
    const float* rcb  = (const float*)d_in[7];
    const float* bias = (const float*)d_in[8];
    float* out = (float*)d_out;

    const int R    = in_sizes[2];
    const int DIN  = in_sizes[1] / R;
    const int M    = in_sizes[0] / DIN;
    const int DOUT = in_sizes[8];

    const size_t szX = (size_t)M * DIN * sizeof(bf16);
    const size_t szU = (size_t)DIN * R * sizeof(bf16);
    const size_t szZ = (size_t)R * DOUT * sizeof(bf16);
    const size_t szV = (size_t)M * R * sizeof(bf16);
    const size_t need = 2 * (szX + szU + szZ + szV);

    const int KT1 = DIN / 32;
    const int KT2 = R / 32;

    if (ws_size >= need && KT1 == 128 && KT2 == 64) {
        char* w = (char*)d_ws;
        bf16* Xh = (bf16*)w;            w += szX;
        bf16* Xl = (bf16*)w;            w += szX;
        bf16* Uh = (bf16*)w;            w += szU;
        bf16* Ul = (bf16*)w;            w += szU;
        bf16* Zh = (bf16*)w;            w += szZ;
        bf16* Zl = (bf16*)w;            w += szZ;
        bf16* Vh = (bf16*)w;            w += szV;
        bf16* Vl = (bf16*)w;

        split_ew_tiled<<<dim3(DIN / 32, M / 128), dim3(256), 0, stream>>>(
            X, Xh, Xl, DIN);
        split_tr_tiled<<<dim3(DIN / 32, R / 128), dim3(256), 0, stream>>>(
            U, Uh, Ul, R);
        split_tr_tiled<<<dim3(R / 32, DOUT / 128), dim3(256), 0, stream>>>(
            Zw, Zh, Zl, DOUT);

        qlin_mfmaC<1, 128><<<dim3(R / BN2, M / BM), dim3(512), 0, stream>>>(
            Xh, Xl, Uh, Ul, M, R, nullptr, Vh, Vl,
            lx, lw, dx, cb, rcb, nullptr);
        qlin_mfmaC<2, 64><<<dim3(DOUT / BN2, M / BM), dim3(512), 0, stream>>>(
            Vh, Vl, Zh, Zl, M, DOUT, out, nullptr, nullptr,
            nullptr, nullptr, nullptr, nullptr, nullptr, bias);
    } else {
        float* V = (float*)d_ws;
        qlin_mfma<1><<<dim3(R / BN, M / BM), dim3(256), 0, stream>>>(
            X, U, V, M, R, DIN, lx, lw, dx, cb, rcb, nullptr);
        qlin_mfma<2><<<dim3(DOUT / BN, M / BM), dim3(256), 0, stream>>>(
            V, Zw, out, M, DOUT, R, nullptr, nullptr, nullptr, nullptr, nullptr, bias);
    }
}